// Round 4
// baseline (254.686 us; speedup 1.0000x reference)
//
#include <hip/hip_runtime.h>

#define EPSF 1e-12f
#define NKNOTS 30
#define NINT 29

typedef float fvec4 __attribute__((ext_vector_type(4)));

// Uniform knots linspace(0,1,30): s = clamp(x*29, 0, 29), idx = min((int)s, 28),
// t = s - idx. Per-interval cubic y = c.x + t*(c.y + t*(c.z + t*c.w)).
// Coefficients in AoS LDS (29 x float4): one ds_read_b128 per eval.
//
// KEY CHANGE vs round 3: round 3's straight-line 16-load block was REORDERED
// by the machine scheduler (VGPR_Count=36 proved loads were sunk next to
// their evals -> ~1 load in flight, same schedule as round 1). This version
// pins the schedule with __builtin_amdgcn_sched_barrier(0) between the load
// block and the eval block: nothing may cross, so all 16 load results must
// be live across the fence (VGPR ~100+) and all 16 global_load_dwordx4 issue
// before the first eval. 16 KB outstanding per wave makes HBM saturation
// independent of memory latency (Little's law: 256KB/CU in flight even at
// 4 waves/SIMD).

__global__ __launch_bounds__(256) void SimpleSpline_kernel(
    const float* __restrict__ x,
    const float* __restrict__ knots,
    const float* __restrict__ coeffs,
    float* __restrict__ out,
    int n)
{
    __shared__ fvec4 cf[NINT];
    __shared__ float dsh[NKNOTS];

    const int tid = threadIdx.x;

    // ---- PCHIP slopes d[tid] (replicates reference math) ----
    if (tid < NKNOTS) {
        float d;
        if (tid == 0) {
            float h0 = knots[1] - knots[0];
            float h1 = knots[2] - knots[1];
            float de0 = (coeffs[1] - coeffs[0]) / (h0 + EPSF);
            float de1 = (coeffs[2] - coeffs[1]) / (h1 + EPSF);
            d = ((2.0f * h0 + h1) * de0 - h0 * de1) / (h0 + h1 + EPSF);
            if (d * de0 <= 0.0f) d = 0.0f;
            if (fabsf(d) > 3.0f * fabsf(de0)) d = 3.0f * de0;
        } else if (tid == NKNOTS - 1) {
            float hN = knots[NKNOTS - 1] - knots[NKNOTS - 2];
            float hM = knots[NKNOTS - 2] - knots[NKNOTS - 3];
            float deN = (coeffs[NKNOTS - 1] - coeffs[NKNOTS - 2]) / (hN + EPSF);
            float deM = (coeffs[NKNOTS - 2] - coeffs[NKNOTS - 3]) / (hM + EPSF);
            d = ((2.0f * hN + hM) * deN - hN * deM) / (hN + hM + EPSF);
            if (d * deN <= 0.0f) d = 0.0f;
            if (fabsf(d) > 3.0f * fabsf(deN)) d = 3.0f * deN;
        } else {
            float hkm1 = knots[tid] - knots[tid - 1];
            float hk   = knots[tid + 1] - knots[tid];
            float dkm1 = (coeffs[tid] - coeffs[tid - 1]) / (hkm1 + EPSF);
            float dk   = (coeffs[tid + 1] - coeffs[tid]) / (hk + EPSF);
            float w1 = 2.0f * hk + hkm1;
            float w2 = hk + 2.0f * hkm1;
            d = 0.0f;
            if (dkm1 * dk > 0.0f)
                d = (w1 + w2) / (w1 / (dkm1 + EPSF) + w2 / (dk + EPSF));
        }
        dsh[tid] = d;
    }
    __syncthreads();

    // ---- per-interval Hermite -> cubic-in-t coefficients (AoS float4) ----
    if (tid < NINT) {
        float h = knots[tid + 1] - knots[tid];
        float safe_h = (fabsf(h) < EPSF) ? 1.0f : h;
        float yk  = coeffs[tid];
        float yk1 = coeffs[tid + 1];
        float sdk  = safe_h * dsh[tid];
        float sdk1 = safe_h * dsh[tid + 1];
        fvec4 c;
        c.x = yk;
        c.y = sdk;
        c.z = 3.0f * (yk1 - yk) - 2.0f * sdk - sdk1;
        c.w = 2.0f * (yk - yk1) + sdk + sdk1;
        cf[tid] = c;
    }
    __syncthreads();

    auto eval1 = [&](float xi) -> float {
        float s = fminf(fmaxf(xi * 29.0f, 0.0f), 29.0f);
        int idx = (int)s;                      // trunc == floor, s >= 0
        idx = idx > (NINT - 1) ? (NINT - 1) : idx;
        float t = s - (float)idx;
        fvec4 c = cf[idx];                     // ds_read_b128
        return fmaf(t, fmaf(t, fmaf(t, c.w, c.z), c.y), c.x);
    };

    const int n4 = n >> 2;
    const int stride = gridDim.x * blockDim.x;
    const int i0 = blockIdx.x * blockDim.x + tid;
    const fvec4* __restrict__ xv = (const fvec4*)x;
    fvec4* __restrict__ ov = (fvec4*)out;

    if (n4 == (stride << 4)) {
        // ---- specialized path: exactly 16 float4s/thread, zero guards ----
#define LD(k) fvec4 v##k = xv[i0 + (k) * stride]
#define EV(k) { fvec4 r;                                   \
                r.x = eval1(v##k.x); r.y = eval1(v##k.y);  \
                r.z = eval1(v##k.z); r.w = eval1(v##k.w);  \
                __builtin_nontemporal_store(r, &ov[i0 + (k) * stride]); }
        LD(0);  LD(1);  LD(2);  LD(3);
        LD(4);  LD(5);  LD(6);  LD(7);
        LD(8);  LD(9);  LD(10); LD(11);
        LD(12); LD(13); LD(14); LD(15);
        // HARD scheduling fence: loads may not sink below, evals may not
        // hoist above. Forces all 16 results live -> 16-deep MLP per wave.
        __builtin_amdgcn_sched_barrier(0);
        EV(0);  EV(1);  EV(2);  EV(3);
        EV(4);  EV(5);  EV(6);  EV(7);
        EV(8);  EV(9);  EV(10); EV(11);
        EV(12); EV(13); EV(14); EV(15);
#undef LD
#undef EV
        return;
    }

    // ---- generic fallback: simple grid-stride ----
    for (int i = i0; i < n4; i += stride) {
        fvec4 v = xv[i];
        fvec4 r;
        r.x = eval1(v.x);
        r.y = eval1(v.y);
        r.z = eval1(v.z);
        r.w = eval1(v.w);
        __builtin_nontemporal_store(r, &ov[i]);
    }

    // scalar tail (n % 4)
    const int rem = n & 3;
    if (rem) {
        const int tbase = n4 << 2;
        if (i0 < rem) out[tbase + i0] = eval1(x[tbase + i0]);
    }
}

extern "C" void kernel_launch(void* const* d_in, const int* in_sizes, int n_in,
                              void* d_out, int out_size, void* d_ws, size_t ws_size,
                              hipStream_t stream) {
    const float* x      = (const float*)d_in[0];
    const float* knots  = (const float*)d_in[1];
    const float* coeffs = (const float*)d_in[2];
    float* out = (float*)d_out;
    const int n = in_sizes[0];

    const int block = 256;
    int n4 = n >> 2;

    // Prefer a grid where each thread owns exactly 16 float4s (guard-free
    // max-MLP path); else fall back to 2048-block grid-stride.
    int blocks;
    if (n4 >= (block << 4) && (n4 % (block << 4)) == 0) {
        blocks = n4 / (block << 4);
        if (blocks > 16384) blocks = 2048;   // absurd n: just grid-stride
    } else {
        blocks = (n4 + block - 1) / block;
        if (blocks > 2048) blocks = 2048;
    }
    if (blocks < 1) blocks = 1;

    SimpleSpline_kernel<<<blocks, block, 0, stream>>>(x, knots, coeffs, out, n);
}

// Round 5
// 241.030 us; speedup vs baseline: 1.0567x; 1.0567x over previous
//
#include <hip/hip_runtime.h>

#define EPSF 1e-12f
#define NKNOTS 30
#define NINT 29

typedef float fvec4 __attribute__((ext_vector_type(4)));

// Uniform knots linspace(0,1,30): s = clamp(x*29, 0, 29), idx = min((int)s, 28),
// t = s - idx. Per-interval cubic y = c.x + t*(c.y + t*(c.z + t*c.w)).
// Coefficients in AoS LDS (29 x float4): one ds_read_b128 per eval.
//
// Ladder so far (kernel dispatch time):
//   r1 grid-stride, 0 prefetch:            78 us, 3.4 TB/s  (duty ~55%)
//   r2 guarded 4-batch:  predicated/sunk   86 us  (VGPR=32: no MLP formed)
//   r3 straight-line 16: scheduler sank    88 us  (VGPR=36: no MLP formed)
//   r4 sched_barrier(0) 16-burst:         103 us  (burst/drain phases ->
//                                          memory IDLE during eval, 2.0 TB/s)
// Lesson: need CONTINUOUS load pressure, not a burst. This version: rotating
// 6-buffer fully-unrolled pipeline "EV(k); LD(k+6)". WAR dep on the buffer
// orders each load after its consumer; sched_barrier(0xFFFFFFDF) = "all may
// cross EXCEPT VMEM_READ" pins each load's position (stops the known sinking)
// while letting VALU/DS/stores interleave freely. Steady state ~5 loads/wave
// in flight at all times.

__global__ __launch_bounds__(256) void SimpleSpline_kernel(
    const float* __restrict__ x,
    const float* __restrict__ knots,
    const float* __restrict__ coeffs,
    float* __restrict__ out,
    int n)
{
    __shared__ fvec4 cf[NINT];
    __shared__ float dsh[NKNOTS];

    const int tid = threadIdx.x;

    // ---- PCHIP slopes d[tid] (replicates reference math) ----
    if (tid < NKNOTS) {
        float d;
        if (tid == 0) {
            float h0 = knots[1] - knots[0];
            float h1 = knots[2] - knots[1];
            float de0 = (coeffs[1] - coeffs[0]) / (h0 + EPSF);
            float de1 = (coeffs[2] - coeffs[1]) / (h1 + EPSF);
            d = ((2.0f * h0 + h1) * de0 - h0 * de1) / (h0 + h1 + EPSF);
            if (d * de0 <= 0.0f) d = 0.0f;
            if (fabsf(d) > 3.0f * fabsf(de0)) d = 3.0f * de0;
        } else if (tid == NKNOTS - 1) {
            float hN = knots[NKNOTS - 1] - knots[NKNOTS - 2];
            float hM = knots[NKNOTS - 2] - knots[NKNOTS - 3];
            float deN = (coeffs[NKNOTS - 1] - coeffs[NKNOTS - 2]) / (hN + EPSF);
            float deM = (coeffs[NKNOTS - 2] - coeffs[NKNOTS - 3]) / (hM + EPSF);
            d = ((2.0f * hN + hM) * deN - hN * deM) / (hN + hM + EPSF);
            if (d * deN <= 0.0f) d = 0.0f;
            if (fabsf(d) > 3.0f * fabsf(deN)) d = 3.0f * deN;
        } else {
            float hkm1 = knots[tid] - knots[tid - 1];
            float hk   = knots[tid + 1] - knots[tid];
            float dkm1 = (coeffs[tid] - coeffs[tid - 1]) / (hkm1 + EPSF);
            float dk   = (coeffs[tid + 1] - coeffs[tid]) / (hk + EPSF);
            float w1 = 2.0f * hk + hkm1;
            float w2 = hk + 2.0f * hkm1;
            d = 0.0f;
            if (dkm1 * dk > 0.0f)
                d = (w1 + w2) / (w1 / (dkm1 + EPSF) + w2 / (dk + EPSF));
        }
        dsh[tid] = d;
    }
    __syncthreads();

    // ---- per-interval Hermite -> cubic-in-t coefficients (AoS float4) ----
    if (tid < NINT) {
        float h = knots[tid + 1] - knots[tid];
        float safe_h = (fabsf(h) < EPSF) ? 1.0f : h;
        float yk  = coeffs[tid];
        float yk1 = coeffs[tid + 1];
        float sdk  = safe_h * dsh[tid];
        float sdk1 = safe_h * dsh[tid + 1];
        fvec4 c;
        c.x = yk;
        c.y = sdk;
        c.z = 3.0f * (yk1 - yk) - 2.0f * sdk - sdk1;
        c.w = 2.0f * (yk - yk1) + sdk + sdk1;
        cf[tid] = c;
    }
    __syncthreads();

    auto eval1 = [&](float xi) -> float {
        float s = fminf(fmaxf(xi * 29.0f, 0.0f), 29.0f);
        int idx = (int)s;                      // trunc == floor, s >= 0
        idx = idx > (NINT - 1) ? (NINT - 1) : idx;
        float t = s - (float)idx;
        fvec4 c = cf[idx];                     // ds_read_b128
        return fmaf(t, fmaf(t, fmaf(t, c.w, c.z), c.y), c.x);
    };

    const int n4 = n >> 2;
    const int stride = gridDim.x * blockDim.x;
    const int i0 = blockIdx.x * blockDim.x + tid;
    const fvec4* __restrict__ xv = (const fvec4*)x;
    fvec4* __restrict__ ov = (fvec4*)out;

    if (n4 == (stride << 4)) {
        // ---- specialized path: exactly 16 float4s/thread, zero guards ----
        // Rotating 6-buffer pipeline, fully unrolled (static buffer names).
#define LDP(vb, kk) do { vb = xv[i0 + (kk) * stride];                       \
                         __builtin_amdgcn_sched_barrier(0xFFFFFFDFu);       \
                    } while (0)
#define EVS(vb, kk) do { fvec4 r;                                           \
                         r.x = eval1(vb.x); r.y = eval1(vb.y);              \
                         r.z = eval1(vb.z); r.w = eval1(vb.w);              \
                         __builtin_nontemporal_store(r, &ov[i0 + (kk) * stride]); \
                    } while (0)
        fvec4 v0, v1, v2, v3, v4, v5;
        // prologue: fill the pipe (6 loads in flight)
        LDP(v0, 0);  LDP(v1, 1);  LDP(v2, 2);
        LDP(v3, 3);  LDP(v4, 4);  LDP(v5, 5);
        // steady state: consume one buffer, refill it for k+6
        EVS(v0, 0);   LDP(v0, 6);
        EVS(v1, 1);   LDP(v1, 7);
        EVS(v2, 2);   LDP(v2, 8);
        EVS(v3, 3);   LDP(v3, 9);
        EVS(v4, 4);   LDP(v4, 10);
        EVS(v5, 5);   LDP(v5, 11);
        EVS(v0, 6);   LDP(v0, 12);
        EVS(v1, 7);   LDP(v1, 13);
        EVS(v2, 8);   LDP(v2, 14);
        EVS(v3, 9);   LDP(v3, 15);
        // drain
        EVS(v4, 10);
        EVS(v5, 11);
        EVS(v0, 12);
        EVS(v1, 13);
        EVS(v2, 14);
        EVS(v3, 15);
#undef LDP
#undef EVS
        // tail (n % 4) — unreachable for the bench shape but kept for safety
        const int rem = n & 3;
        if (rem) {
            const int tbase = n4 << 2;
            if (i0 < rem) out[tbase + i0] = eval1(x[tbase + i0]);
        }
        return;
    }

    // ---- generic fallback: simple grid-stride ----
    for (int i = i0; i < n4; i += stride) {
        fvec4 v = xv[i];
        fvec4 r;
        r.x = eval1(v.x);
        r.y = eval1(v.y);
        r.z = eval1(v.z);
        r.w = eval1(v.w);
        __builtin_nontemporal_store(r, &ov[i]);
    }

    // scalar tail (n % 4)
    const int rem = n & 3;
    if (rem) {
        const int tbase = n4 << 2;
        if (i0 < rem) out[tbase + i0] = eval1(x[tbase + i0]);
    }
}

extern "C" void kernel_launch(void* const* d_in, const int* in_sizes, int n_in,
                              void* d_out, int out_size, void* d_ws, size_t ws_size,
                              hipStream_t stream) {
    const float* x      = (const float*)d_in[0];
    const float* knots  = (const float*)d_in[1];
    const float* coeffs = (const float*)d_in[2];
    float* out = (float*)d_out;
    const int n = in_sizes[0];

    const int block = 256;
    int n4 = n >> 2;

    // Prefer a grid where each thread owns exactly 16 float4s (guard-free
    // pipelined path); else fall back to 2048-block grid-stride.
    int blocks;
    if (n4 >= (block << 4) && (n4 % (block << 4)) == 0) {
        blocks = n4 / (block << 4);
        if (blocks > 16384) blocks = 2048;   // absurd n: just grid-stride
    } else {
        blocks = (n4 + block - 1) / block;
        if (blocks > 2048) blocks = 2048;
    }
    if (blocks < 1) blocks = 1;

    SimpleSpline_kernel<<<blocks, block, 0, stream>>>(x, knots, coeffs, out, n);
}

// Round 6
// 224.439 us; speedup vs baseline: 1.1348x; 1.0739x over previous
//
#include <hip/hip_runtime.h>

#define EPSF 1e-12f
#define NKNOTS 30
#define NINT 29

typedef float fvec4 __attribute__((ext_vector_type(4)));

// Uniform knots linspace(0,1,30): s = clamp(x*29, 0, 29), idx = min((int)s, 28),
// t = s - idx. Per-interval cubic y = c.x + t*(c.y + t*(c.z + t*c.w)).
//
// Ladder (kernel dispatch time):
//   old session: 32768 blk x 1 float4/thread:  ~73 us  <- best known
//   r1 2048-blk grid-stride + nt:               78 us, 3.4 TB/s
//   r2/r3/r5 source-level MLP pipelines:     85-88 us (compiler sank loads,
//                                             VGPR 32-36: batches never live)
//   r4 sched_barrier(0) 16-burst:             103 us (burst/drain, 2.0 TB/s)
// Lesson: block-churn (many small blocks) is the effective pipeline on this
// chip; per-wave software MLP keeps getting undone. So keep the best-known
// structure and remove its one measurable overhead: the per-block PCHIP
// preamble (~10-deep dependent global-load + divergent-math chain + 2
// barriers, paid by all 32768 blocks). A tiny setup kernel precomputes the
// 29 x float4 coefficient table into d_ws; the main kernel preamble becomes
// one coalesced 464B load + one barrier, and the x-load issues BEFORE the
// preamble so its ~900cy latency hides under the table load + barrier.

__global__ __launch_bounds__(64) void spline_setup_kernel(
    const float* __restrict__ knots,
    const float* __restrict__ coeffs,
    fvec4* __restrict__ cft)
{
    __shared__ float dsh[NKNOTS];
    const int tid = threadIdx.x;

    if (tid < NKNOTS) {
        float d;
        if (tid == 0) {
            float h0 = knots[1] - knots[0];
            float h1 = knots[2] - knots[1];
            float de0 = (coeffs[1] - coeffs[0]) / (h0 + EPSF);
            float de1 = (coeffs[2] - coeffs[1]) / (h1 + EPSF);
            d = ((2.0f * h0 + h1) * de0 - h0 * de1) / (h0 + h1 + EPSF);
            if (d * de0 <= 0.0f) d = 0.0f;
            if (fabsf(d) > 3.0f * fabsf(de0)) d = 3.0f * de0;
        } else if (tid == NKNOTS - 1) {
            float hN = knots[NKNOTS - 1] - knots[NKNOTS - 2];
            float hM = knots[NKNOTS - 2] - knots[NKNOTS - 3];
            float deN = (coeffs[NKNOTS - 1] - coeffs[NKNOTS - 2]) / (hN + EPSF);
            float deM = (coeffs[NKNOTS - 2] - coeffs[NKNOTS - 3]) / (hM + EPSF);
            d = ((2.0f * hN + hM) * deN - hN * deM) / (hN + hM + EPSF);
            if (d * deN <= 0.0f) d = 0.0f;
            if (fabsf(d) > 3.0f * fabsf(deN)) d = 3.0f * deN;
        } else {
            float hkm1 = knots[tid] - knots[tid - 1];
            float hk   = knots[tid + 1] - knots[tid];
            float dkm1 = (coeffs[tid] - coeffs[tid - 1]) / (hkm1 + EPSF);
            float dk   = (coeffs[tid + 1] - coeffs[tid]) / (hk + EPSF);
            float w1 = 2.0f * hk + hkm1;
            float w2 = hk + 2.0f * hkm1;
            d = 0.0f;
            if (dkm1 * dk > 0.0f)
                d = (w1 + w2) / (w1 / (dkm1 + EPSF) + w2 / (dk + EPSF));
        }
        dsh[tid] = d;
    }
    __syncthreads();

    if (tid < NINT) {
        float h = knots[tid + 1] - knots[tid];
        float safe_h = (fabsf(h) < EPSF) ? 1.0f : h;
        float yk  = coeffs[tid];
        float yk1 = coeffs[tid + 1];
        float sdk  = safe_h * dsh[tid];
        float sdk1 = safe_h * dsh[tid + 1];
        fvec4 c;
        c.x = yk;
        c.y = sdk;
        c.z = 3.0f * (yk1 - yk) - 2.0f * sdk - sdk1;
        c.w = 2.0f * (yk - yk1) + sdk + sdk1;
        cft[tid] = c;
    }
}

__global__ __launch_bounds__(256) void SimpleSpline_kernel(
    const float* __restrict__ x,
    const fvec4* __restrict__ cft,
    float* __restrict__ out,
    int n)
{
    __shared__ fvec4 cf[NINT];

    const int tid = threadIdx.x;
    const int n4 = n >> 2;
    const int gi = blockIdx.x * blockDim.x + tid;

    // Issue the x-load FIRST, unconditionally (clamped index: no exec-mask
    // guard to trigger predication/sinking). Its latency hides under the
    // table load + barrier below.
    const fvec4* __restrict__ xv = (const fvec4*)x;
    int gil = gi < n4 ? gi : (n4 > 0 ? n4 - 1 : 0);
    fvec4 v = xv[gil];

    // Slim preamble: one coalesced 464B load + LDS write + barrier.
    if (tid < NINT) cf[tid] = cft[tid];
    __syncthreads();

    auto eval1 = [&](float xi) -> float {
        float s = fminf(fmaxf(xi * 29.0f, 0.0f), 29.0f);
        int idx = (int)s;                      // trunc == floor, s >= 0
        idx = idx > (NINT - 1) ? (NINT - 1) : idx;
        float t = s - (float)idx;
        fvec4 c = cf[idx];                     // ds_read_b128
        return fmaf(t, fmaf(t, fmaf(t, c.w, c.z), c.y), c.x);
    };

    if (gi < n4) {
        fvec4 r;
        r.x = eval1(v.x);
        r.y = eval1(v.y);
        r.z = eval1(v.z);
        r.w = eval1(v.w);
        ((fvec4*)out)[gi] = r;                 // plain store (best-known cfg)
    }

    // scalar tail (n % 4)
    const int rem = n & 3;
    if (rem) {
        const int tbase = n4 << 2;
        if (gi < rem) out[tbase + gi] = eval1(x[tbase + gi]);
    }
}

// Fallback (workspace unavailable): self-contained, same math, per-block setup.
__global__ __launch_bounds__(256) void SimpleSpline_kernel_self(
    const float* __restrict__ x,
    const float* __restrict__ knots,
    const float* __restrict__ coeffs,
    float* __restrict__ out,
    int n)
{
    __shared__ fvec4 cf[NINT];
    __shared__ float dsh[NKNOTS];
    const int tid = threadIdx.x;

    if (tid < NKNOTS) {
        float d;
        if (tid == 0) {
            float h0 = knots[1] - knots[0];
            float h1 = knots[2] - knots[1];
            float de0 = (coeffs[1] - coeffs[0]) / (h0 + EPSF);
            float de1 = (coeffs[2] - coeffs[1]) / (h1 + EPSF);
            d = ((2.0f * h0 + h1) * de0 - h0 * de1) / (h0 + h1 + EPSF);
            if (d * de0 <= 0.0f) d = 0.0f;
            if (fabsf(d) > 3.0f * fabsf(de0)) d = 3.0f * de0;
        } else if (tid == NKNOTS - 1) {
            float hN = knots[NKNOTS - 1] - knots[NKNOTS - 2];
            float hM = knots[NKNOTS - 2] - knots[NKNOTS - 3];
            float deN = (coeffs[NKNOTS - 1] - coeffs[NKNOTS - 2]) / (hN + EPSF);
            float deM = (coeffs[NKNOTS - 2] - coeffs[NKNOTS - 3]) / (hM + EPSF);
            d = ((2.0f * hN + hM) * deN - hN * deM) / (hN + hM + EPSF);
            if (d * deN <= 0.0f) d = 0.0f;
            if (fabsf(d) > 3.0f * fabsf(deN)) d = 3.0f * deN;
        } else {
            float hkm1 = knots[tid] - knots[tid - 1];
            float hk   = knots[tid + 1] - knots[tid];
            float dkm1 = (coeffs[tid] - coeffs[tid - 1]) / (hkm1 + EPSF);
            float dk   = (coeffs[tid + 1] - coeffs[tid]) / (hk + EPSF);
            float w1 = 2.0f * hk + hkm1;
            float w2 = hk + 2.0f * hkm1;
            d = 0.0f;
            if (dkm1 * dk > 0.0f)
                d = (w1 + w2) / (w1 / (dkm1 + EPSF) + w2 / (dk + EPSF));
        }
        dsh[tid] = d;
    }
    __syncthreads();

    if (tid < NINT) {
        float h = knots[tid + 1] - knots[tid];
        float safe_h = (fabsf(h) < EPSF) ? 1.0f : h;
        float yk  = coeffs[tid];
        float yk1 = coeffs[tid + 1];
        float sdk  = safe_h * dsh[tid];
        float sdk1 = safe_h * dsh[tid + 1];
        fvec4 c;
        c.x = yk;
        c.y = sdk;
        c.z = 3.0f * (yk1 - yk) - 2.0f * sdk - sdk1;
        c.w = 2.0f * (yk - yk1) + sdk + sdk1;
        cf[tid] = c;
    }
    __syncthreads();

    auto eval1 = [&](float xi) -> float {
        float s = fminf(fmaxf(xi * 29.0f, 0.0f), 29.0f);
        int idx = (int)s;
        idx = idx > (NINT - 1) ? (NINT - 1) : idx;
        float t = s - (float)idx;
        fvec4 c = cf[idx];
        return fmaf(t, fmaf(t, fmaf(t, c.w, c.z), c.y), c.x);
    };

    const int n4 = n >> 2;
    const int gi = blockIdx.x * blockDim.x + tid;
    if (gi < n4) {
        fvec4 v = ((const fvec4*)x)[gi];
        fvec4 r;
        r.x = eval1(v.x);
        r.y = eval1(v.y);
        r.z = eval1(v.z);
        r.w = eval1(v.w);
        ((fvec4*)out)[gi] = r;
    }
    const int rem = n & 3;
    if (rem) {
        const int tbase = n4 << 2;
        if (gi < rem) out[tbase + gi] = eval1(x[tbase + gi]);
    }
}

extern "C" void kernel_launch(void* const* d_in, const int* in_sizes, int n_in,
                              void* d_out, int out_size, void* d_ws, size_t ws_size,
                              hipStream_t stream) {
    const float* x      = (const float*)d_in[0];
    const float* knots  = (const float*)d_in[1];
    const float* coeffs = (const float*)d_in[2];
    float* out = (float*)d_out;
    const int n = in_sizes[0];

    const int block = 256;
    int n4 = n >> 2;
    int blocks = (n4 + block - 1) / block;   // bench shape: exactly 32768
    if (blocks < 1) blocks = 1;

    if (d_ws != nullptr && ws_size >= NINT * sizeof(fvec4)) {
        fvec4* cft = (fvec4*)d_ws;
        spline_setup_kernel<<<1, 64, 0, stream>>>(knots, coeffs, cft);
        SimpleSpline_kernel<<<blocks, block, 0, stream>>>(x, cft, out, n);
    } else {
        SimpleSpline_kernel_self<<<blocks, block, 0, stream>>>(x, knots, coeffs, out, n);
    }
}